// Round 2
// baseline (179.145 us; speedup 1.0000x reference)
//
#include <hip/hip_runtime.h>
#include <hip/hip_bf16.h>
#include <math.h>

#define N_TOK 8192
#define D_IN  768
#define D_OUT 64
#define WAVES 8
#define KVB   32

typedef __attribute__((ext_vector_type(8))) short short8;
typedef __attribute__((ext_vector_type(4))) short short4v;
typedef __attribute__((ext_vector_type(4))) float f32x4;

// f32 -> bf16 bits, round-to-nearest-even
__device__ __forceinline__ short f2bf(float f) {
  union { float f; unsigned u; } v; v.f = f;
  unsigned r = v.u + 0x7fffu + ((v.u >> 16) & 1u);
  return (short)(r >> 16);
}
__device__ __forceinline__ unsigned pack2(float lo, float hi) {
  return (unsigned)(unsigned short)f2bf(lo) | ((unsigned)(unsigned short)f2bf(hi) << 16);
}

// ---------------------------------------------------------------------------
// Fused projection: stage X tile once, compute X@Wq, X@Wk, X@Wv.
//   Q pre-scaled by log2(e)/8 (folds softmax scale + exp->exp2)
//   V stored transposed Vt[d][n]
// ---------------------------------------------------------------------------
__global__ __launch_bounds__(256) void proj_kernel(
    const float* __restrict__ X,
    const float* __restrict__ Wq, const float* __restrict__ Wk,
    const float* __restrict__ Wv,
    short* __restrict__ Q, short* __restrict__ K, short* __restrict__ Vt)
{
  __shared__ short Xs[64][40];
  __shared__ short Ws[3][64][40];   // W^T tiles: [which][col][k]

  const int t  = threadIdx.x;
  const int w  = t >> 6;
  const int l  = t & 63;
  const int g  = l >> 4;
  const int lr = l & 15;
  const int r0 = blockIdx.x * 64;
  const float* Wall[3] = {Wq, Wk, Wv};

  f32x4 acc[3][4] = {};

  for (int kb = 0; kb < D_IN; kb += 32) {
    {
      const int row = t >> 2, kc = (t & 3) * 8;
      const float* src = X + (size_t)(r0 + row) * D_IN + kb + kc;
      short8 v;
      #pragma unroll
      for (int i = 0; i < 8; ++i) v[i] = f2bf(src[i]);
      *reinterpret_cast<short8*>(&Xs[row][kc]) = v;
    }
    {
      const int col = t & 63, k0 = (t >> 6) * 8;
      #pragma unroll
      for (int which = 0; which < 3; ++which)
        #pragma unroll
        for (int i = 0; i < 8; ++i)
          Ws[which][col][k0 + i] = f2bf(Wall[which][(size_t)(kb + k0 + i) * D_OUT + col]);
    }
    __syncthreads();

    short8 a = *reinterpret_cast<const short8*>(&Xs[w * 16 + lr][g * 8]);
    #pragma unroll
    for (int which = 0; which < 3; ++which)
      #pragma unroll
      for (int dt = 0; dt < 4; ++dt) {
        short8 b = *reinterpret_cast<const short8*>(&Ws[which][dt * 16 + lr][g * 8]);
        acc[which][dt] = __builtin_amdgcn_mfma_f32_16x16x32_bf16(a, b, acc[which][dt], 0, 0, 0);
      }
    __syncthreads();
  }

  // C/D layout: col = lane&15, row = g*4 + r
  const int rb = r0 + w * 16 + g * 4;
  const float QS = 0.18033688011112042f;  // log2(e) / sqrt(64)
  #pragma unroll
  for (int dt = 0; dt < 4; ++dt)
    #pragma unroll
    for (int r = 0; r < 4; ++r) {
      Q[(size_t)(rb + r) * D_OUT + dt * 16 + lr] = f2bf(acc[0][dt][r] * QS);
      K[(size_t)(rb + r) * D_OUT + dt * 16 + lr] = f2bf(acc[1][dt][r]);
    }
  #pragma unroll
  for (int dt = 0; dt < 4; ++dt) {
    short4v pv;
    #pragma unroll
    for (int r = 0; r < 4; ++r) pv[r] = f2bf(acc[2][dt][r]);
    *reinterpret_cast<short4v*>(&Vt[(size_t)(dt * 16 + lr) * N_TOK + rb]) = pv;
  }
}

// ---------------------------------------------------------------------------
// Flash attention, swapped-operand MFMA layout:
//   S = mfma(K,Q): lane holds S[kv in regs][q = lane&15]  -> in-reg row max
//   O^T = mfma(Vt,P): lane holds O[d in regs][q = lane&15] -> in-lane rescale
// Defer-max (THR=8): steady-state iteration has ZERO cross-lane ops.
// 8 waves/block, each wave owns 1024 KV rows; LDS merge at the end.
// ---------------------------------------------------------------------------
__global__ __launch_bounds__(512) void attn_kernel(
    const short* __restrict__ Q, const short* __restrict__ K,
    const short* __restrict__ Vt, float* __restrict__ out)
{
  __shared__ short Pb[WAVES][16][40];     // per-wave P tile [q][kv], padded
  __shared__ float Opart[WAVES][16][68];  // padded stride 68 (bank spread)
  __shared__ float mpart[WAVES][16];
  __shared__ float lpart[WAVES][16];

  const int t  = threadIdx.x;
  const int w  = t >> 6;
  const int l  = t & 63;
  const int g  = l >> 4;
  const int lr = l & 15;
  const int q0 = blockIdx.x * 16;

  // Q b-frag: lane holds Q[q0 + lr][g*8 ..], k split in two chunks
  const short* qp = Q + (size_t)(q0 + lr) * D_OUT + g * 8;
  short8 aq0 = *reinterpret_cast<const short8*>(qp);
  short8 aq1 = *reinterpret_cast<const short8*>(qp + 32);

  float m = -INFINITY, lsum = 0.0f;
  f32x4 o[4] = {};

  const int kv0 = w * (N_TOK / WAVES);

  for (int it = 0; it < (N_TOK / WAVES) / KVB; ++it) {
    const int kvb = kv0 + it * KVB;

    // S^T tiles: s[jt][r] = S[kv = kvb + jt*16 + g*4 + r][q = lr]
    f32x4 s[2] = {};
    #pragma unroll
    for (int jt = 0; jt < 2; ++jt) {
      const short* kp = K + (size_t)(kvb + jt * 16 + lr) * D_OUT + g * 8;
      short8 b0 = *reinterpret_cast<const short8*>(kp);
      short8 b1 = *reinterpret_cast<const short8*>(kp + 32);
      s[jt] = __builtin_amdgcn_mfma_f32_16x16x32_bf16(b0, aq0, s[jt], 0, 0, 0);
      s[jt] = __builtin_amdgcn_mfma_f32_16x16x32_bf16(b1, aq1, s[jt], 0, 0, 0);
    }

    // in-register local max over this lane's 8 kv values
    float lmax = fmaxf(fmaxf(fmaxf(s[0][0], s[0][1]), fmaxf(s[0][2], s[0][3])),
                       fmaxf(fmaxf(s[1][0], s[1][1]), fmaxf(s[1][2], s[1][3])));

    // defer-max: only touch cross-lane + rescale when max grows past THR=8
    if (!__all(lmax <= m + 8.0f)) {
      float wm = fmaxf(lmax, __shfl_xor(lmax, 16));
      wm = fmaxf(wm, __shfl_xor(wm, 32));
      const float mnew = fmaxf(m, wm);
      const float sc = __builtin_amdgcn_exp2f(m - mnew);  // first iter: 0
      #pragma unroll
      for (int dt = 0; dt < 4; ++dt) o[dt] *= sc;
      lsum *= sc;
      m = mnew;
    }

    // p = exp2(s - m), accumulate per-lane partial row-sum (reduced once at end)
    float p[2][4];
    #pragma unroll
    for (int jt = 0; jt < 2; ++jt)
      #pragma unroll
      for (int r = 0; r < 4; ++r) {
        p[jt][r] = __builtin_amdgcn_exp2f(s[jt][r] - m);
        lsum += p[jt][r];
      }

    // P -> LDS [q][kv] (transpose via u32 pair writes), then b-frag read
    unsigned* pw = reinterpret_cast<unsigned*>(&Pb[w][lr][0]);
    #pragma unroll
    for (int jt = 0; jt < 2; ++jt) {
      pw[jt * 8 + g * 2 + 0] = pack2(p[jt][0], p[jt][1]);
      pw[jt * 8 + g * 2 + 1] = pack2(p[jt][2], p[jt][3]);
    }
    short8 pbf = *reinterpret_cast<const short8*>(&Pb[w][lr][g * 8]);

    // O^T += Vt * P : o[dt][r] = O[d = dt*16 + g*4 + r][q = lr]
    #pragma unroll
    for (int dt = 0; dt < 4; ++dt) {
      short8 av = *reinterpret_cast<const short8*>(
          Vt + (size_t)(dt * 16 + lr) * N_TOK + kvb + g * 8);
      o[dt] = __builtin_amdgcn_mfma_f32_16x16x32_bf16(av, pbf, o[dt], 0, 0, 0);
    }
  }

  // deferred l-sum reduce across the 4 lane-groups sharing each q
  lsum += __shfl_xor(lsum, 16);
  lsum += __shfl_xor(lsum, 32);

  // publish per-wave partials
  #pragma unroll
  for (int dt = 0; dt < 4; ++dt)
    *reinterpret_cast<f32x4*>(&Opart[w][lr][dt * 16 + g * 4]) = o[dt];
  if (l < 16) { mpart[w][l] = m; lpart[w][l] = lsum; }
  __syncthreads();

  // merge 8 wave partials; 512 threads cover 16x64 outputs in 2 passes
  for (int i = t; i < 16 * 64; i += 512) {
    const int qq = i >> 6, d = i & 63;
    float M = mpart[0][qq];
    #pragma unroll
    for (int w2 = 1; w2 < WAVES; ++w2) M = fmaxf(M, mpart[w2][qq]);
    float num = 0.0f, den = 0.0f;
    #pragma unroll
    for (int w2 = 0; w2 < WAVES; ++w2) {
      const float e = __builtin_amdgcn_exp2f(mpart[w2][qq] - M);
      num += e * Opart[w2][qq][d];
      den += e * lpart[w2][qq];
    }
    out[(size_t)(q0 + qq) * D_OUT + d] = num / den;
  }
}

extern "C" void kernel_launch(void* const* d_in, const int* in_sizes, int n_in,
                              void* d_out, int out_size, void* d_ws, size_t ws_size,
                              hipStream_t stream) {
  const float* X  = (const float*)d_in[0];
  const float* Wq = (const float*)d_in[1];
  const float* Wk = (const float*)d_in[2];
  const float* Wv = (const float*)d_in[3];

  short* Q  = (short*)d_ws;                       // [8192][64] bf16 (pre-scaled)
  short* K  = Q + (size_t)N_TOK * D_OUT;          // [8192][64] bf16
  short* Vt = K + (size_t)N_TOK * D_OUT;          // [64][8192] bf16
  float* out = (float*)d_out;

  hipLaunchKernelGGL(proj_kernel, dim3(N_TOK / 64), dim3(256), 0, stream,
                     X, Wq, Wk, Wv, Q, K, Vt);
  hipLaunchKernelGGL(attn_kernel, dim3(N_TOK / 16), dim3(512), 0, stream,
                     Q, K, Vt, out);
}